// Round 7
// baseline (16487.520 us; speedup 1.0000x reference)
//
#include <hip/hip_runtime.h>

#define HDIM 96
#define G4   384
#define LSEQ 32768
#define BATCH 8
#define TCH   1024
#define NCH   (LSEQ / TCH)

#define L2E  1.4426950408889634f
#define SNEG (-L2E)        /* sigmoid gates: exp(-x) = exp2(SNEG*x) */
#define SPOS (2.0f * L2E)  /* tanh gates:    exp(2x) = exp2(SPOS*x) */

typedef __fp16 v2h __attribute__((ext_vector_type(2)));

__device__ __forceinline__ v2h u2h(unsigned u) {
    union { unsigned u; v2h h; } c; c.u = u; return c.h;
}

__device__ __forceinline__ float tanh_(float x) {    // raw argument (c state)
    // overflow-safe: exp2 -> inf => rcp -> 0 => tanh -> 1. NO fused form here.
    return fmaf(-2.f, __builtin_amdgcn_rcpf(1.f + __builtin_amdgcn_exp2f(SPOS * x)), 1.f);
}

// 8-lane butterfly sum on the VALU pipe (DPP), zero DS-pipe usage.
#define DPPSTEP(v, CTRL) { \
    int t_ = __builtin_amdgcn_update_dpp(0, __float_as_int(v), CTRL, 0xF, 0xF, true); \
    v += __int_as_float(t_); }
#define RED8(v) DPPSTEP(v, 0xB1) DPPSTEP(v, 0x4E) DPPSTEP(v, 0x141)

// quad_perm broadcast: all lanes of each quad read quad-lane L of src.
#define QBCAST(DST, SRCI, CTRL) \
    float DST = __int_as_float(__builtin_amdgcn_update_dpp(0, (SRCI), (CTRL), 0xF, 0xF, true));

// Lite barrier: LDS ordering only; global ops stay in flight.
#define BARL() asm volatile("s_waitcnt lgkmcnt(0)\n\ts_barrier" ::: "memory")

#define PIN4x3(A,B,C) asm volatile("" : \
  "+v"(A.x),"+v"(A.y),"+v"(A.z),"+v"(A.w), \
  "+v"(B.x),"+v"(B.y),"+v"(B.z),"+v"(B.w), \
  "+v"(C.x),"+v"(C.y),"+v"(C.z),"+v"(C.w));

#define SC4(V, S) { V.x *= (S); V.y *= (S); V.z *= (S); V.w *= (S); }

// Thread owns all 4 gate rows of element e x cols [12s, 12s+12).
// Weights pre-scaled per gate (f32), then packed to fp16 pairs: the MV runs
// on v_dot2_f32_f16 (2 MACs/op, f32 accumulate). c-state / x-path / xp / head
// all stay f32 — only the recurrent MV operands are fp16.
#define WLOADPIN_H(W) \
    const float4* pI = reinterpret_cast<const float4*>((W) + (size_t)e        * HDIM + 12*s); \
    const float4* pF = reinterpret_cast<const float4*>((W) + (size_t)(96 + e) * HDIM + 12*s); \
    const float4* pG = reinterpret_cast<const float4*>((W) + (size_t)(192+ e) * HDIM + 12*s); \
    const float4* pO = reinterpret_cast<const float4*>((W) + (size_t)(288+ e) * HDIM + 12*s); \
    float4 tI0=pI[0], tI1=pI[1], tI2=pI[2]; \
    float4 tF0=pF[0], tF1=pF[1], tF2=pF[2]; \
    float4 tG0=pG[0], tG1=pG[1], tG2=pG[2]; \
    float4 tO0=pO[0], tO1=pO[1], tO2=pO[2]; \
    SC4(tI0,SNEG) SC4(tI1,SNEG) SC4(tI2,SNEG) \
    SC4(tF0,SNEG) SC4(tF1,SNEG) SC4(tF2,SNEG) \
    SC4(tG0,SPOS) SC4(tG1,SPOS) SC4(tG2,SPOS) \
    SC4(tO0,SNEG) SC4(tO1,SNEG) SC4(tO2,SNEG) \
    v2h wI0=__builtin_amdgcn_cvt_pkrtz(tI0.x,tI0.y), wI1=__builtin_amdgcn_cvt_pkrtz(tI0.z,tI0.w), \
        wI2=__builtin_amdgcn_cvt_pkrtz(tI1.x,tI1.y), wI3=__builtin_amdgcn_cvt_pkrtz(tI1.z,tI1.w), \
        wI4=__builtin_amdgcn_cvt_pkrtz(tI2.x,tI2.y), wI5=__builtin_amdgcn_cvt_pkrtz(tI2.z,tI2.w); \
    v2h wF0=__builtin_amdgcn_cvt_pkrtz(tF0.x,tF0.y), wF1=__builtin_amdgcn_cvt_pkrtz(tF0.z,tF0.w), \
        wF2=__builtin_amdgcn_cvt_pkrtz(tF1.x,tF1.y), wF3=__builtin_amdgcn_cvt_pkrtz(tF1.z,tF1.w), \
        wF4=__builtin_amdgcn_cvt_pkrtz(tF2.x,tF2.y), wF5=__builtin_amdgcn_cvt_pkrtz(tF2.z,tF2.w); \
    v2h wG0=__builtin_amdgcn_cvt_pkrtz(tG0.x,tG0.y), wG1=__builtin_amdgcn_cvt_pkrtz(tG0.z,tG0.w), \
        wG2=__builtin_amdgcn_cvt_pkrtz(tG1.x,tG1.y), wG3=__builtin_amdgcn_cvt_pkrtz(tG1.z,tG1.w), \
        wG4=__builtin_amdgcn_cvt_pkrtz(tG2.x,tG2.y), wG5=__builtin_amdgcn_cvt_pkrtz(tG2.z,tG2.w); \
    v2h wO0=__builtin_amdgcn_cvt_pkrtz(tO0.x,tO0.y), wO1=__builtin_amdgcn_cvt_pkrtz(tO0.z,tO0.w), \
        wO2=__builtin_amdgcn_cvt_pkrtz(tO1.x,tO1.y), wO3=__builtin_amdgcn_cvt_pkrtz(tO1.z,tO1.w), \
        wO4=__builtin_amdgcn_cvt_pkrtz(tO2.x,tO2.y), wO5=__builtin_amdgcn_cvt_pkrtz(tO2.z,tO2.w); \
    asm volatile("" : "+v"(wI0),"+v"(wI1),"+v"(wI2),"+v"(wI3),"+v"(wI4),"+v"(wI5), \
                      "+v"(wF0),"+v"(wF1),"+v"(wF2),"+v"(wF3),"+v"(wF4),"+v"(wF5)); \
    asm volatile("" : "+v"(wG0),"+v"(wG1),"+v"(wG2),"+v"(wG3),"+v"(wG4),"+v"(wG5), \
                      "+v"(wO0),"+v"(wO1),"+v"(wO2),"+v"(wO3),"+v"(wO4),"+v"(wO5));

// fp16 h fragment read: 12 halves = 24B = 3x ds_read_b64, 8B-aligned,
// bank-conflict-free (addr/4 mod 32 distinct across s).
#define HRD(RO) \
    const uint2* hp = reinterpret_cast<const uint2*>(hs_h + (RO) + 12 * s); \
    uint2 ha = hp[0], hb = hp[1], hc = hp[2];

// 4-gate interleaved dot2 (ILP=4, 6-deep chains — mirrors the proven MVK).
#define MVD6(HV, k) { v2h hv_ = (HV); \
  gi = __builtin_amdgcn_fdot2(wI##k, hv_, gi, false); \
  gf = __builtin_amdgcn_fdot2(wF##k, hv_, gf, false); \
  gg = __builtin_amdgcn_fdot2(wG##k, hv_, gg, false); \
  go = __builtin_amdgcn_fdot2(wO##k, hv_, go, false); }

// Transposed batched activation tail (proven R5): lane s picks gate (s&3),
// ONE exp2 + ONE rcp + map-fma, quad_perm broadcast back.
#define GATES_TAIL(DEST_STORE) \
    RED8(gg) RED8(gi) RED8(gf) RED8(go) \
    float v_ = (s & 2) ? ((s & 1) ? go : gg) : ((s & 1) ? gf : gi); \
    float E_ = __builtin_amdgcn_exp2f(v_); \
    float r_ = __builtin_amdgcn_rcpf(1.f + E_); \
    int ai = __float_as_int(fmaf(mC, r_, aC)); \
    QBCAST(si, ai, 0x00) \
    QBCAST(sf, ai, 0x55) \
    QBCAST(tg, ai, 0xAA) \
    QBCAST(so, ai, 0xFF) \
    cU = fmaf(sf, cU, si * tg); \
    float hN = so * tanh_(cU); \
    DEST_STORE

// One LSTM step, role 0. RO = LDS read offset (0/96 halves, compile-time).
#define STEP0(RO, XT) { \
    HRD(RO) \
    float gi = fmaf(wiI, (XT), bbI); \
    float gf = fmaf(wiF, (XT), bbF); \
    float gg = fmaf(wiG, (XT), bbG); \
    float go = fmaf(wiO, (XT), bbO); \
    MVD6(u2h(ha.x),0) MVD6(u2h(ha.y),1) MVD6(u2h(hb.x),2) \
    MVD6(u2h(hb.y),3) MVD6(u2h(hc.x),4) MVD6(u2h(hc.y),5) \
    GATES_TAIL( \
      if (w0l) { hs_h[((RO) ^ HDIM) + e] = (__fp16)hN; *hobp = hN; } \
      hobp += HDIM; ) }

// One LSTM step, role 2. xp (f32-exact, pre-scaled by gate-const/8 at role 1)
// folds into the accumulator init; butterfly restores the full value.
#define STEP2(RO, XPV) { \
    HRD(RO) \
    float gi = (XPV).x, gf = (XPV).y, gg = (XPV).z, go = (XPV).w; \
    MVD6(u2h(ha.x),0) MVD6(u2h(ha.y),1) MVD6(u2h(hb.x),2) \
    MVD6(u2h(hb.y),3) MVD6(u2h(hc.x),4) MVD6(u2h(hc.y),5) \
    GATES_TAIL( \
      if (w0l) { hs_h[((RO) ^ HDIM) + e] = (__fp16)hN; *h1p = hN; } \
      h1p += HDIM; ) }

#define WAIT_GE(PTR, VAL) \
    while (__hip_atomic_load((PTR), __ATOMIC_ACQUIRE, __HIP_MEMORY_SCOPE_AGENT) < (VAL)) \
        __builtin_amdgcn_s_sleep(2);

#define SIGNAL(PTR, VAL) \
    __hip_atomic_store((PTR), (VAL), __ATOMIC_RELEASE, __HIP_MEMORY_SCOPE_AGENT);

__global__ void init_flags(int* flags) {
    if (threadIdx.x < 64) flags[threadIdx.x] = 0;
}

// ---------------------------------------------------------------------------
// 32 blocks, 4 roles:
//   0..7   producer : L0 scan (fp16-dot2 DPP core, x8 unroll) -> h0buf, flag0
//   8..15  xp worker: flag0 -> xp ring depth 2 in (t,e,gate)-float4, flag1
//   16..23 consumer : flag1 -> L1 scan (fp16-dot2 DPP core) -> h1 ring, flag2
//   24..31 head     : flag2 -> out, flag3 (h1 slot reuse)
// ---------------------------------------------------------------------------
__global__ void __launch_bounds__(768)
__attribute__((amdgpu_waves_per_eu(3, 3)))
lstm_pipe(const float* __restrict__ x,
          const float* __restrict__ Wih0, const float* __restrict__ Whh0, const float* __restrict__ b0v,
          const float* __restrict__ Wih1, const float* __restrict__ Whh1, const float* __restrict__ b1v,
          const float* __restrict__ h0v,  const float* __restrict__ c0v,
          const float* __restrict__ headw,const float* __restrict__ headb,
          float* __restrict__ h0buf, float* __restrict__ xpbuf, float* __restrict__ h1buf,
          int* flags, float* __restrict__ out)
{
    const int tid  = threadIdx.x;
    const int lane = tid & 63;
    const int e    = tid >> 3;     // element 0..95
    const int s    = tid & 7;      // 12-col segment 0..7
    const bool w0l = ((lane & 7) == 0);

    int* flag0 = flags;
    int* flag1 = flags + 8;
    int* flag2 = flags + 16;
    int* flag3 = flags + 24;

    __shared__ __align__(16) __fp16 hs_h[2 * HDIM];
    __shared__ __align__(16) float h_sh[32 * HDIM];
    __shared__ float ph_sh[2 * G4];          // tt-parity double buffer

    const int role = blockIdx.x >> 3;
    const int bidx = blockIdx.x & 7;

    // map-fma constants for the transposed tail (loop-invariant per thread)
    const float mC = ((s & 3) == 2) ? -2.f : 1.f;
    const float aC = ((s & 3) == 2) ?  1.f : 0.f;

    if (role == 0) {
        // =================== producer: L0 scan ===================
        WLOADPIN_H(Whh0)
        // input weights + bias pre-scaled by gate-const and 1/8 (butterfly
        // sums 8 identical copies back to full value — exact). f32 path.
        const float wiI = Wih0[e]      * (SNEG * 0.125f);
        const float wiF = Wih0[96 + e] * (SNEG * 0.125f);
        const float wiG = Wih0[192+ e] * (SPOS * 0.125f);
        const float wiO = Wih0[288+ e] * (SNEG * 0.125f);
        const float bbI = b0v[e]       * (SNEG * 0.125f);
        const float bbF = b0v[96 + e]  * (SNEG * 0.125f);
        const float bbG = b0v[192+ e]  * (SPOS * 0.125f);
        const float bbO = b0v[288+ e]  * (SNEG * 0.125f);

        float cU = c0v[e];
        if (w0l) hs_h[e] = (__fp16)h0v[e];
        __syncthreads();

        const float* xb  = x + (size_t)bidx * LSEQ;
        float*       hobp = h0buf + (size_t)bidx * LSEQ * HDIM + e;

        float4 xA = *reinterpret_cast<const float4*>(xb);   // t = 0..3

#pragma unroll 1
        for (int gI = 0; gI < LSEQ / 8; ++gI) {
            float4 xB = *reinterpret_cast<const float4*>(xb + gI * 8 + 4);
            STEP0(0,    xA.x) BARL();
            STEP0(HDIM, xA.y) BARL();
            STEP0(0,    xA.z) BARL();
            STEP0(HDIM, xA.w) BARL();
            float4 xAn = *reinterpret_cast<const float4*>(
                xb + (((gI + 1) * 8 < LSEQ) ? (gI + 1) * 8 : LSEQ - 8));
            STEP0(0,    xB.x) BARL();
            STEP0(HDIM, xB.y) BARL();
            STEP0(0,    xB.z) BARL();
            STEP0(HDIM, xB.w)
            xA = xAn;
            if (((gI + 1) & 127) == 0) {      // t+1 = 8(gI+1) ≡ 0 mod TCH
                __threadfence();
                __syncthreads();
                if (tid == 0) SIGNAL(&flag0[bidx], (gI + 1) >> 7)
            } else {
                BARL();
            }
        }
    } else if (role == 1) {
        // =================== xp worker (f32-exact) ===================
        const bool halfx = (tid >= G4);
        const int  g     = halfx ? tid - G4 : tid;
        const int  dstoff = (g % 96) * 4 + (g / 96);   // (e,gate) float4 layout
        // gate-const AND 1/8: role 2 folds xp into the accumulator init and
        // the 8-lane butterfly multiplies it back (exact, power of two).
        const float gsc  = (((g / 96) == 2) ? SPOS : SNEG) * 0.125f;
        const float4* Wxp = reinterpret_cast<const float4*>(Wih1 + (size_t)g * HDIM + (halfx ? 48 : 0));
        const float xbias = halfx ? 0.f : b1v[g] * gsc;

        float4 q0=Wxp[0],q1=Wxp[1],q2=Wxp[2],q3=Wxp[3],q4=Wxp[4],q5=Wxp[5],
               q6=Wxp[6],q7=Wxp[7],q8=Wxp[8],q9=Wxp[9],q10=Wxp[10],q11=Wxp[11];
        SC4(q0,gsc) SC4(q1,gsc) SC4(q2,gsc)  SC4(q3,gsc) SC4(q4,gsc)  SC4(q5,gsc)
        SC4(q6,gsc) SC4(q7,gsc) SC4(q8,gsc)  SC4(q9,gsc) SC4(q10,gsc) SC4(q11,gsc)
        PIN4x3(q0,q1,q2) PIN4x3(q3,q4,q5) PIN4x3(q6,q7,q8) PIN4x3(q9,q10,q11)

        const float* hsrcB = h0buf + (size_t)bidx * LSEQ * HDIM;

#pragma unroll 1
        for (int k = 0; k < NCH; ++k) {
            if (tid == 0) {
                WAIT_GE(&flag0[bidx], k + 1)
                if (k >= 2) WAIT_GE(&flag2[bidx], k - 1)
            }
            __syncthreads();
            __threadfence();

            const float* hsrc = hsrcB + (size_t)k * TCH * HDIM;
            float* xpd = xpbuf + ((size_t)bidx * 2 + (k & 1)) * TCH * G4;

#pragma unroll 1
            for (int t0 = 0; t0 < TCH; t0 += 32) {
                // 32*96 floats = exactly one float4 per thread
                reinterpret_cast<float4*>(h_sh)[tid] =
                    reinterpret_cast<const float4*>(hsrc + (size_t)t0 * HDIM)[tid];
                BARL();
#pragma unroll 1
                for (int tt = 0; tt < 32; ++tt) {
                    const float4* h4 = reinterpret_cast<const float4*>(
                        h_sh + tt * HDIM + (halfx ? 48 : 0));
                    float a0 = xbias, a1 = 0.f, a2 = 0.f, a3 = 0.f;
                    float4 hv;
                    hv=h4[0];  a0=fmaf(q0.x, hv.x,a0); a1=fmaf(q0.y, hv.y,a1); a2=fmaf(q0.z, hv.z,a2); a3=fmaf(q0.w, hv.w,a3);
                    hv=h4[1];  a0=fmaf(q1.x, hv.x,a0); a1=fmaf(q1.y, hv.y,a1); a2=fmaf(q1.z, hv.z,a2); a3=fmaf(q1.w, hv.w,a3);
                    hv=h4[2];  a0=fmaf(q2.x, hv.x,a0); a1=fmaf(q2.y, hv.y,a1); a2=fmaf(q2.z, hv.z,a2); a3=fmaf(q2.w, hv.w,a3);
                    hv=h4[3];  a0=fmaf(q3.x, hv.x,a0); a1=fmaf(q3.y, hv.y,a1); a2=fmaf(q3.z, hv.z,a2); a3=fmaf(q3.w, hv.w,a3);
                    hv=h4[4];  a0=fmaf(q4.x, hv.x,a0); a1=fmaf(q4.y, hv.y,a1); a2=fmaf(q4.z, hv.z,a2); a3=fmaf(q4.w, hv.w,a3);
                    hv=h4[5];  a0=fmaf(q5.x, hv.x,a0); a1=fmaf(q5.y, hv.y,a1); a2=fmaf(q5.z, hv.z,a2); a3=fmaf(q5.w, hv.w,a3);
                    hv=h4[6];  a0=fmaf(q6.x, hv.x,a0); a1=fmaf(q6.y, hv.y,a1); a2=fmaf(q6.z, hv.z,a2); a3=fmaf(q6.w, hv.w,a3);
                    hv=h4[7];  a0=fmaf(q7.x, hv.x,a0); a1=fmaf(q7.y, hv.y,a1); a2=fmaf(q7.z, hv.z,a2); a3=fmaf(q7.w, hv.w,a3);
                    hv=h4[8];  a0=fmaf(q8.x, hv.x,a0); a1=fmaf(q8.y, hv.y,a1); a2=fmaf(q8.z, hv.z,a2); a3=fmaf(q8.w, hv.w,a3);
                    hv=h4[9];  a0=fmaf(q9.x, hv.x,a0); a1=fmaf(q9.y, hv.y,a1); a2=fmaf(q9.z, hv.z,a2); a3=fmaf(q9.w, hv.w,a3);
                    hv=h4[10]; a0=fmaf(q10.x,hv.x,a0); a1=fmaf(q10.y,hv.y,a1); a2=fmaf(q10.z,hv.z,a2); a3=fmaf(q10.w,hv.w,a3);
                    hv=h4[11]; a0=fmaf(q11.x,hv.x,a0); a1=fmaf(q11.y,hv.y,a1); a2=fmaf(q11.z,hv.z,a2); a3=fmaf(q11.w,hv.w,a3);
                    float part = (a0 + a1) + (a2 + a3);
                    float* ph2 = ph_sh + ((tt & 1) ? G4 : 0);   // parity dbuf
                    if (halfx) ph2[g] = part;
                    BARL();
                    if (!halfx) xpd[(size_t)(t0 + tt) * G4 + dstoff] = part + ph2[g];
                }
                BARL();   // protect h_sh + ph slot reuse before next stage
            }
            __threadfence();
            __syncthreads();
            if (tid == 0) SIGNAL(&flag1[bidx], k + 1)
        }
    } else if (role == 2) {
        // =================== consumer: L1 scan ===================
        WLOADPIN_H(Whh1)

        float cU = c0v[HDIM + e];
        if (w0l) hs_h[e] = (__fp16)h0v[HDIM + e];
        __syncthreads();

#pragma unroll 1
        for (int k = 0; k < NCH; ++k) {
            if (tid == 0) {
                WAIT_GE(&flag1[bidx], k + 1)
                if (k >= 2) WAIT_GE(&flag3[bidx], k - 1)
            }
            __syncthreads();
            __threadfence();

            const float4* xq  = reinterpret_cast<const float4*>(
                xpbuf + ((size_t)bidx * 2 + (k & 1)) * TCH * G4) + e;
            float* h1p = h1buf + ((size_t)bidx * 2 + (k & 1)) * TCH * HDIM + e;

            float4 a0 = xq[0], a1 = xq[HDIM], a2 = xq[2 * HDIM], a3 = xq[3 * HDIM];

#pragma unroll 1
            for (int gI = 0; gI < TCH / 8; ++gI) {
                const float4* xg = xq + (size_t)gI * 8 * HDIM;
                float4 b0_, b1_, b2_, b3_;
                STEP2(0,    a0) b0_ = xg[4 * HDIM]; BARL();
                STEP2(HDIM, a1) b1_ = xg[5 * HDIM]; BARL();
                STEP2(0,    a2) b2_ = xg[6 * HDIM]; BARL();
                STEP2(HDIM, a3) b3_ = xg[7 * HDIM]; BARL();
                const float4* xn = xq + (size_t)((gI + 1 < TCH / 8) ? (gI + 1) * 8 : TCH - 8) * HDIM;
                STEP2(0,    b0_) a0 = xn[0];        BARL();
                STEP2(HDIM, b1_) a1 = xn[HDIM];     BARL();
                STEP2(0,    b2_) a2 = xn[2 * HDIM]; BARL();
                STEP2(HDIM, b3_) a3 = xn[3 * HDIM]; BARL();
            }
            __threadfence();
            __syncthreads();
            if (tid == 0) SIGNAL(&flag2[bidx], k + 1)
        }
    } else {
        // =================== head (f32) ===================
        const float hb = headb[0];
        float4 wv[24];
#pragma unroll
        for (int j = 0; j < 24; ++j) wv[j] = reinterpret_cast<const float4*>(headw)[j];

#pragma unroll 1
        for (int k = 0; k < NCH; ++k) {
            if (tid == 0) WAIT_GE(&flag2[bidx], k + 1)
            __syncthreads();
            __threadfence();

            const float* h1c = h1buf + ((size_t)bidx * 2 + (k & 1)) * TCH * HDIM;
            for (int t = tid; t < TCH; t += 768) {
                const float4* hp = reinterpret_cast<const float4*>(h1c + (size_t)t * HDIM);
                float s2 = 0.f;
#pragma unroll
                for (int j = 0; j < 24; ++j) {
                    float4 a = hp[j], b = wv[j];
                    s2 = fmaf(a.x, b.x, s2); s2 = fmaf(a.y, b.y, s2);
                    s2 = fmaf(a.z, b.z, s2); s2 = fmaf(a.w, b.w, s2);
                }
                out[(size_t)bidx * LSEQ + (size_t)k * TCH + t] = s2 + hb;
            }
            __threadfence();
            __syncthreads();
            if (tid == 0) SIGNAL(&flag3[bidx], k + 1)
        }
    }
}

// ---------------------------------------------------------------------------
extern "C" void kernel_launch(void* const* d_in, const int* in_sizes, int n_in,
                              void* d_out, int out_size, void* d_ws, size_t ws_size,
                              hipStream_t stream)
{
    const float* x     = (const float*)d_in[0];
    const float* Wih0  = (const float*)d_in[1];
    const float* Whh0  = (const float*)d_in[2];
    const float* b0    = (const float*)d_in[3];
    const float* Wih1  = (const float*)d_in[4];
    const float* Whh1  = (const float*)d_in[5];
    const float* b1    = (const float*)d_in[6];
    const float* h0    = (const float*)d_in[7];
    const float* c0    = (const float*)d_in[8];
    const float* headw = (const float*)d_in[9];
    const float* headb = (const float*)d_in[10];
    float* out = (float*)d_out;

    char* ws = (char*)d_ws;
    const size_t h0bytes = (size_t)BATCH * LSEQ * HDIM * sizeof(float);    // 100.7 MB
    const size_t xpbytes = (size_t)BATCH * 2 * TCH * G4 * sizeof(float);   // 25.2 MB
    const size_t h1bytes = (size_t)BATCH * 2 * TCH * HDIM * sizeof(float); // 6.3 MB

    float* h0buf = (float*)ws;
    float* xpbuf = (float*)(ws + h0bytes);
    float* h1buf = (float*)(ws + h0bytes + xpbytes);
    int*   flags = (int*)  (ws + h0bytes + xpbytes + h1bytes);

    init_flags<<<1, 64, 0, stream>>>(flags);
    lstm_pipe<<<32, 768, 0, stream>>>(x, Wih0, Whh0, b0, Wih1, Whh1, b1,
                                      h0, c0, headw, headb,
                                      h0buf, xpbuf, h1buf, flags, out);
}

// Round 9
// 14190.736 us; speedup vs baseline: 1.1619x; 1.1619x over previous
//
#include <hip/hip_runtime.h>

#define HDIM 96
#define G4   384
#define LSEQ 32768
#define BATCH 8
#define TCH   1024
#define NCH   (LSEQ / TCH)

#define L2E  1.4426950408889634f
#define SNEG (-L2E)        /* sigmoid gates: exp(-x) = exp2(SNEG*x) */
#define SPOS (2.0f * L2E)  /* tanh gates:    exp(2x) = exp2(SPOS*x) */

__device__ __forceinline__ float tanh_(float x) {    // raw argument (c state)
    // overflow-safe: exp2 -> inf => rcp -> 0 => tanh -> 1. NO fused form here.
    return fmaf(-2.f, __builtin_amdgcn_rcpf(1.f + __builtin_amdgcn_exp2f(SPOS * x)), 1.f);
}

// DPP helpers (VALU pipe, zero DS usage).
#define DPPSTEP(v, CTRL) { \
    int t_ = __builtin_amdgcn_update_dpp(0, __float_as_int(v), CTRL, 0xF, 0xF, true); \
    v += __int_as_float(t_); }
#define DPPADDV(u, v, CTRL) { \
    int t_ = __builtin_amdgcn_update_dpp(0, __float_as_int(v), CTRL, 0xF, 0xF, true); \
    u += __int_as_float(t_); }

// quad_perm broadcast: all lanes of each quad read quad-lane L of src.
#define QBCAST(DST, SRCI, CTRL) \
    float DST = __int_as_float(__builtin_amdgcn_update_dpp(0, (SRCI), (CTRL), 0xF, 0xF, true));

// Lite barrier: LDS ordering only; global ops stay in flight.
#define BARL() asm volatile("s_waitcnt lgkmcnt(0)\n\ts_barrier" ::: "memory")

#define PIN4x3(A,B,C) asm volatile("" : \
  "+v"(A.x),"+v"(A.y),"+v"(A.z),"+v"(A.w), \
  "+v"(B.x),"+v"(B.y),"+v"(B.z),"+v"(B.w), \
  "+v"(C.x),"+v"(C.y),"+v"(C.z),"+v"(C.w));

#define SC4(V, S) { V.x *= (S); V.y *= (S); V.z *= (S); V.w *= (S); }

// Thread owns all 4 gate rows of element e x cols [12s, 12s+12).
// Weights pre-scaled per gate for exp2-direct activations. f32 scalar MVK
// with 4-gate interleave (ILP=4) is the proven structure (R3: pk_fma
// regressed; R7: fdot2 fp16 regressed — both extended the latency chain).
#define WLOADPIN(W) \
    const float4* pI = reinterpret_cast<const float4*>((W) + (size_t)e        * HDIM + 12*s); \
    const float4* pF = reinterpret_cast<const float4*>((W) + (size_t)(96 + e) * HDIM + 12*s); \
    const float4* pG = reinterpret_cast<const float4*>((W) + (size_t)(192+ e) * HDIM + 12*s); \
    const float4* pO = reinterpret_cast<const float4*>((W) + (size_t)(288+ e) * HDIM + 12*s); \
    float4 wI0=pI[0], wI1=pI[1], wI2=pI[2]; \
    float4 wF0=pF[0], wF1=pF[1], wF2=pF[2]; \
    float4 wG0=pG[0], wG1=pG[1], wG2=pG[2]; \
    float4 wO0=pO[0], wO1=pO[1], wO2=pO[2]; \
    SC4(wI0,SNEG) SC4(wI1,SNEG) SC4(wI2,SNEG) \
    SC4(wF0,SNEG) SC4(wF1,SNEG) SC4(wF2,SNEG) \
    SC4(wG0,SPOS) SC4(wG1,SPOS) SC4(wG2,SPOS) \
    SC4(wO0,SNEG) SC4(wO1,SNEG) SC4(wO2,SNEG) \
    PIN4x3(wI0,wI1,wI2) PIN4x3(wF0,wF1,wF2) PIN4x3(wG0,wG1,wG2) PIN4x3(wO0,wO1,wO2)

#define MVK(n, hv) \
  gi=fmaf(wI##n.x,hv.x,gi); gi=fmaf(wI##n.y,hv.y,gi); gi=fmaf(wI##n.z,hv.z,gi); gi=fmaf(wI##n.w,hv.w,gi); \
  gf=fmaf(wF##n.x,hv.x,gf); gf=fmaf(wF##n.y,hv.y,gf); gf=fmaf(wF##n.z,hv.z,gf); gf=fmaf(wF##n.w,hv.w,gf); \
  gg=fmaf(wG##n.x,hv.x,gg); gg=fmaf(wG##n.y,hv.y,gg); gg=fmaf(wG##n.z,hv.z,gg); gg=fmaf(wG##n.w,hv.w,gg); \
  go=fmaf(wO##n.x,hv.x,go); go=fmaf(wO##n.y,hv.y,go); go=fmaf(wO##n.z,hv.z,go); go=fmaf(wO##n.w,hv.w,go);

// Merged transposing reduction + batched activation tail, MIRROR-SYMMETRIC.
// R8 bug: round 3 (row_half_mirror 0x141) pairs lane s with 7-s; with gate
// (s&3) on both quads that mixed gate g with gate 3-g. Fix: target layout
// t(s) = (s&3) ^ (s&4 ? 3 : 0)  ->  quad0: i,f,g,o; quad1: o,g,f,i.
// Then lane 7-s carries the SAME gate as lane s and the mirror completes
// each gate's 8-sum. Lane 0's add tree is bitwise-identical to RED8:
// [(g0+g1)+(g2+g3)] + [(g7+g6)+(g5+g4)].
// Quad 0 ends with i,f,g,o at lanes 0..3 -> QBCAST as before. Quad 1's
// QBCAST delivers order-swapped activations -> cU garbage in lanes 4..7,
// harmless: only lane s==0 writes hN, and next-step accumulators are
// freshly re-initialized (no per-lane state crosses steps except lane 0).
#define GATES_TAIL(DEST_STORE) \
    float uA = (tsel & 1) ? gf : gi,  vA = (tsel & 1) ? gi : gf; \
    float uB = (tsel & 1) ? go : gg,  vB = (tsel & 1) ? gg : go; \
    DPPADDV(uA, vA, 0xB1)  DPPADDV(uB, vB, 0xB1) \
    float uC = (tsel & 2) ? uB : uA,  vC = (tsel & 2) ? uA : uB; \
    DPPADDV(uC, vC, 0x4E) \
    DPPSTEP(uC, 0x141) \
    float E_ = __builtin_amdgcn_exp2f(uC); \
    float r_ = __builtin_amdgcn_rcpf(1.f + E_); \
    int ai = __float_as_int(fmaf(mC, r_, aC)); \
    QBCAST(si, ai, 0x00) \
    QBCAST(sf, ai, 0x55) \
    QBCAST(tg, ai, 0xAA) \
    QBCAST(so, ai, 0xFF) \
    cU = fmaf(sf, cU, si * tg); \
    float hN = so * tanh_(cU); \
    DEST_STORE

// One LSTM step, role 0. RO = LDS read offset (0/96, compile-time).
// x-term folded into accumulator INIT (pre-scaled by gate-const/8; the
// 8-lane butterfly sums 8 identical copies back — exact, powers of two).
#define STEP0(RO, XT) { \
    const float4* hp = reinterpret_cast<const float4*>(hs + (RO) + 12 * s); \
    float4 hv0 = hp[0], hv1 = hp[1], hv2 = hp[2]; \
    float gi = fmaf(wiI, (XT), bbI); \
    float gf = fmaf(wiF, (XT), bbF); \
    float gg = fmaf(wiG, (XT), bbG); \
    float go = fmaf(wiO, (XT), bbO); \
    MVK(0, hv0) MVK(1, hv1) MVK(2, hv2) \
    GATES_TAIL( \
      if (w0l) { hs[((RO) ^ HDIM) + e] = hN; *hobp = hN; } \
      hobp += HDIM; ) }

// One LSTM step, role 2. xp (pre-scaled by gate-const/8 at role 1) folds
// into the accumulator init; butterfly restores the full value.
#define STEP2(RO, XPV) { \
    const float4* hp = reinterpret_cast<const float4*>(hs + (RO) + 12 * s); \
    float4 hv0 = hp[0], hv1 = hp[1], hv2 = hp[2]; \
    float gi = (XPV).x, gf = (XPV).y, gg = (XPV).z, go = (XPV).w; \
    MVK(0, hv0) MVK(1, hv1) MVK(2, hv2) \
    GATES_TAIL( \
      if (w0l) { hs[((RO) ^ HDIM) + e] = hN; *h1p = hN; } \
      h1p += HDIM; ) }

#define WAIT_GE(PTR, VAL) \
    while (__hip_atomic_load((PTR), __ATOMIC_ACQUIRE, __HIP_MEMORY_SCOPE_AGENT) < (VAL)) \
        __builtin_amdgcn_s_sleep(2);

#define SIGNAL(PTR, VAL) \
    __hip_atomic_store((PTR), (VAL), __ATOMIC_RELEASE, __HIP_MEMORY_SCOPE_AGENT);

__global__ void init_flags(int* flags) {
    if (threadIdx.x < 64) flags[threadIdx.x] = 0;
}

// ---------------------------------------------------------------------------
// 32 blocks, 4 roles:
//   0..7   producer : L0 scan (DPP core, x8 unroll) -> h0buf, flag0 per chunk
//   8..15  xp worker: flag0 -> xp ring depth 2 in (t,e,gate)-float4, flag1
//   16..23 consumer : flag1 -> L1 scan (DPP core, x8 unroll) -> h1 ring, flag2
//   24..31 head     : flag2 -> out, flag3 (h1 slot reuse)
// ---------------------------------------------------------------------------
__global__ void __launch_bounds__(768)
__attribute__((amdgpu_waves_per_eu(3, 3)))
lstm_pipe(const float* __restrict__ x,
          const float* __restrict__ Wih0, const float* __restrict__ Whh0, const float* __restrict__ b0v,
          const float* __restrict__ Wih1, const float* __restrict__ Whh1, const float* __restrict__ b1v,
          const float* __restrict__ h0v,  const float* __restrict__ c0v,
          const float* __restrict__ headw,const float* __restrict__ headb,
          float* __restrict__ h0buf, float* __restrict__ xpbuf, float* __restrict__ h1buf,
          int* flags, float* __restrict__ out)
{
    const int tid  = threadIdx.x;
    const int lane = tid & 63;
    const int e    = tid >> 3;     // element 0..95
    const int s    = tid & 7;      // 12-col segment 0..7
    const bool w0l = ((lane & 7) == 0);

    int* flag0 = flags;
    int* flag1 = flags + 8;
    int* flag2 = flags + 16;
    int* flag3 = flags + 24;

    __shared__ __align__(16) float hs[2 * HDIM];
    __shared__ __align__(16) float h_sh[32 * HDIM];
    __shared__ float ph_sh[2 * G4];          // tt-parity double buffer

    const int role = blockIdx.x >> 3;
    const int bidx = blockIdx.x & 7;

    // mirror-symmetric gate index for the merged butterfly (loop-invariant):
    // quad 0 -> i,f,g,o ; quad 1 -> o,g,f,i
    const int tsel = (s & 3) ^ ((s & 4) ? 3 : 0);
    // map-fma constants: tanh map on the cell-gate lane (tsel==2)
    const float mC = (tsel == 2) ? -2.f : 1.f;
    const float aC = (tsel == 2) ?  1.f : 0.f;

    if (role == 0) {
        // =================== producer: L0 scan ===================
        WLOADPIN(Whh0)
        // input weights + bias pre-scaled by gate-const and 1/8 (butterfly
        // sums 8 identical copies back to full value — exact).
        const float wiI = Wih0[e]      * (SNEG * 0.125f);
        const float wiF = Wih0[96 + e] * (SNEG * 0.125f);
        const float wiG = Wih0[192+ e] * (SPOS * 0.125f);
        const float wiO = Wih0[288+ e] * (SNEG * 0.125f);
        const float bbI = b0v[e]       * (SNEG * 0.125f);
        const float bbF = b0v[96 + e]  * (SNEG * 0.125f);
        const float bbG = b0v[192+ e]  * (SPOS * 0.125f);
        const float bbO = b0v[288+ e]  * (SNEG * 0.125f);

        float cU = c0v[e];
        if (w0l) hs[e] = h0v[e];
        __syncthreads();

        const float* xb  = x + (size_t)bidx * LSEQ;
        float*       hobp = h0buf + (size_t)bidx * LSEQ * HDIM + e;

        float4 xA = *reinterpret_cast<const float4*>(xb);   // t = 0..3

#pragma unroll 1
        for (int gI = 0; gI < LSEQ / 8; ++gI) {
            float4 xB = *reinterpret_cast<const float4*>(xb + gI * 8 + 4);
            STEP0(0,    xA.x) BARL();
            STEP0(HDIM, xA.y) BARL();
            STEP0(0,    xA.z) BARL();
            STEP0(HDIM, xA.w) BARL();
            float4 xAn = *reinterpret_cast<const float4*>(
                xb + (((gI + 1) * 8 < LSEQ) ? (gI + 1) * 8 : LSEQ - 8));
            STEP0(0,    xB.x) BARL();
            STEP0(HDIM, xB.y) BARL();
            STEP0(0,    xB.z) BARL();
            STEP0(HDIM, xB.w)
            xA = xAn;
            if (((gI + 1) & 127) == 0) {      // t+1 = 8(gI+1) ≡ 0 mod TCH
                __threadfence();
                __syncthreads();
                if (tid == 0) SIGNAL(&flag0[bidx], (gI + 1) >> 7)
            } else {
                BARL();
            }
        }
    } else if (role == 1) {
        // =================== xp worker ===================
        const bool halfx = (tid >= G4);
        const int  g     = halfx ? tid - G4 : tid;
        const int  dstoff = (g % 96) * 4 + (g / 96);   // (e,gate) float4 layout
        // gate-const AND 1/8: role 2 folds xp into the accumulator init and
        // the 8-lane butterfly multiplies it back (exact, power of two).
        const float gsc  = (((g / 96) == 2) ? SPOS : SNEG) * 0.125f;
        const float4* Wxp = reinterpret_cast<const float4*>(Wih1 + (size_t)g * HDIM + (halfx ? 48 : 0));
        const float xbias = halfx ? 0.f : b1v[g] * gsc;

        float4 q0=Wxp[0],q1=Wxp[1],q2=Wxp[2],q3=Wxp[3],q4=Wxp[4],q5=Wxp[5],
               q6=Wxp[6],q7=Wxp[7],q8=Wxp[8],q9=Wxp[9],q10=Wxp[10],q11=Wxp[11];
        SC4(q0,gsc) SC4(q1,gsc) SC4(q2,gsc)  SC4(q3,gsc) SC4(q4,gsc)  SC4(q5,gsc)
        SC4(q6,gsc) SC4(q7,gsc) SC4(q8,gsc)  SC4(q9,gsc) SC4(q10,gsc) SC4(q11,gsc)
        PIN4x3(q0,q1,q2) PIN4x3(q3,q4,q5) PIN4x3(q6,q7,q8) PIN4x3(q9,q10,q11)

        const float* hsrcB = h0buf + (size_t)bidx * LSEQ * HDIM;

#pragma unroll 1
        for (int k = 0; k < NCH; ++k) {
            if (tid == 0) {
                WAIT_GE(&flag0[bidx], k + 1)
                if (k >= 2) WAIT_GE(&flag2[bidx], k - 1)
            }
            __syncthreads();
            __threadfence();

            const float* hsrc = hsrcB + (size_t)k * TCH * HDIM;
            float* xpd = xpbuf + ((size_t)bidx * 2 + (k & 1)) * TCH * G4;

#pragma unroll 1
            for (int t0 = 0; t0 < TCH; t0 += 32) {
                // 32*96 floats = exactly one float4 per thread
                reinterpret_cast<float4*>(h_sh)[tid] =
                    reinterpret_cast<const float4*>(hsrc + (size_t)t0 * HDIM)[tid];
                BARL();
#pragma unroll 1
                for (int tt = 0; tt < 32; ++tt) {
                    const float4* h4 = reinterpret_cast<const float4*>(
                        h_sh + tt * HDIM + (halfx ? 48 : 0));
                    float a0 = xbias, a1 = 0.f, a2 = 0.f, a3 = 0.f;
                    float4 hv;
                    hv=h4[0];  a0=fmaf(q0.x, hv.x,a0); a1=fmaf(q0.y, hv.y,a1); a2=fmaf(q0.z, hv.z,a2); a3=fmaf(q0.w, hv.w,a3);
                    hv=h4[1];  a0=fmaf(q1.x, hv.x,a0); a1=fmaf(q1.y, hv.y,a1); a2=fmaf(q1.z, hv.z,a2); a3=fmaf(q1.w, hv.w,a3);
                    hv=h4[2];  a0=fmaf(q2.x, hv.x,a0); a1=fmaf(q2.y, hv.y,a1); a2=fmaf(q2.z, hv.z,a2); a3=fmaf(q2.w, hv.w,a3);
                    hv=h4[3];  a0=fmaf(q3.x, hv.x,a0); a1=fmaf(q3.y, hv.y,a1); a2=fmaf(q3.z, hv.z,a2); a3=fmaf(q3.w, hv.w,a3);
                    hv=h4[4];  a0=fmaf(q4.x, hv.x,a0); a1=fmaf(q4.y, hv.y,a1); a2=fmaf(q4.z, hv.z,a2); a3=fmaf(q4.w, hv.w,a3);
                    hv=h4[5];  a0=fmaf(q5.x, hv.x,a0); a1=fmaf(q5.y, hv.y,a1); a2=fmaf(q5.z, hv.z,a2); a3=fmaf(q5.w, hv.w,a3);
                    hv=h4[6];  a0=fmaf(q6.x, hv.x,a0); a1=fmaf(q6.y, hv.y,a1); a2=fmaf(q6.z, hv.z,a2); a3=fmaf(q6.w, hv.w,a3);
                    hv=h4[7];  a0=fmaf(q7.x, hv.x,a0); a1=fmaf(q7.y, hv.y,a1); a2=fmaf(q7.z, hv.z,a2); a3=fmaf(q7.w, hv.w,a3);
                    hv=h4[8];  a0=fmaf(q8.x, hv.x,a0); a1=fmaf(q8.y, hv.y,a1); a2=fmaf(q8.z, hv.z,a2); a3=fmaf(q8.w, hv.w,a3);
                    hv=h4[9];  a0=fmaf(q9.x, hv.x,a0); a1=fmaf(q9.y, hv.y,a1); a2=fmaf(q9.z, hv.z,a2); a3=fmaf(q9.w, hv.w,a3);
                    hv=h4[10]; a0=fmaf(q10.x,hv.x,a0); a1=fmaf(q10.y,hv.y,a1); a2=fmaf(q10.z,hv.z,a2); a3=fmaf(q10.w,hv.w,a3);
                    hv=h4[11]; a0=fmaf(q11.x,hv.x,a0); a1=fmaf(q11.y,hv.y,a1); a2=fmaf(q11.z,hv.z,a2); a3=fmaf(q11.w,hv.w,a3);
                    float part = (a0 + a1) + (a2 + a3);
                    float* ph2 = ph_sh + ((tt & 1) ? G4 : 0);   // parity dbuf
                    if (halfx) ph2[g] = part;
                    BARL();
                    if (!halfx) xpd[(size_t)(t0 + tt) * G4 + dstoff] = part + ph2[g];
                }
                BARL();   // protect h_sh + ph slot reuse before next stage
            }
            __threadfence();
            __syncthreads();
            if (tid == 0) SIGNAL(&flag1[bidx], k + 1)
        }
    } else if (role == 2) {
        // =================== consumer: L1 scan ===================
        WLOADPIN(Whh1)

        float cU = c0v[HDIM + e];
        if (w0l) hs[e] = h0v[HDIM + e];
        __syncthreads();

#pragma unroll 1
        for (int k = 0; k < NCH; ++k) {
            if (tid == 0) {
                WAIT_GE(&flag1[bidx], k + 1)
                if (k >= 2) WAIT_GE(&flag3[bidx], k - 1)
            }
            __syncthreads();
            __threadfence();

            const float4* xq  = reinterpret_cast<const float4*>(
                xpbuf + ((size_t)bidx * 2 + (k & 1)) * TCH * G4) + e;
            float* h1p = h1buf + ((size_t)bidx * 2 + (k & 1)) * TCH * HDIM + e;

            float4 a0 = xq[0], a1 = xq[HDIM], a2 = xq[2 * HDIM], a3 = xq[3 * HDIM];

#pragma unroll 1
            for (int gI = 0; gI < TCH / 8; ++gI) {
                const float4* xg = xq + (size_t)gI * 8 * HDIM;
                float4 b0_, b1_, b2_, b3_;
                STEP2(0,    a0) b0_ = xg[4 * HDIM]; BARL();
                STEP2(HDIM, a1) b1_ = xg[5 * HDIM]; BARL();
                STEP2(0,    a2) b2_ = xg[6 * HDIM]; BARL();
                STEP2(HDIM, a3) b3_ = xg[7 * HDIM]; BARL();
                const float4* xn = xq + (size_t)((gI + 1 < TCH / 8) ? (gI + 1) * 8 : TCH - 8) * HDIM;
                STEP2(0,    b0_) a0 = xn[0];        BARL();
                STEP2(HDIM, b1_) a1 = xn[HDIM];     BARL();
                STEP2(0,    b2_) a2 = xn[2 * HDIM]; BARL();
                STEP2(HDIM, b3_) a3 = xn[3 * HDIM]; BARL();
            }
            __threadfence();
            __syncthreads();
            if (tid == 0) SIGNAL(&flag2[bidx], k + 1)
        }
    } else {
        // =================== head ===================
        const float hb = headb[0];
        float4 wv[24];
#pragma unroll
        for (int j = 0; j < 24; ++j) wv[j] = reinterpret_cast<const float4*>(headw)[j];

#pragma unroll 1
        for (int k = 0; k < NCH; ++k) {
            if (tid == 0) WAIT_GE(&flag2[bidx], k + 1)
            __syncthreads();
            __threadfence();

            const float* h1c = h1buf + ((size_t)bidx * 2 + (k & 1)) * TCH * HDIM;
            for (int t = tid; t < TCH; t += 768) {
                const float4* hp = reinterpret_cast<const float4*>(h1c + (size_t)t * HDIM);
                float s2 = 0.f;
#pragma unroll
                for (int j = 0; j < 24; ++j) {
                    float4 a = hp[j], b = wv[j];
                    s2 = fmaf(a.x, b.x, s2); s2 = fmaf(a.y, b.y, s2);
                    s2 = fmaf(a.z, b.z, s2); s2 = fmaf(a.w, b.w, s2);
                }
                out[(size_t)bidx * LSEQ + (size_t)k * TCH + t] = s2 + hb;
            }
            __threadfence();
            __syncthreads();
            if (tid == 0) SIGNAL(&flag3[bidx], k + 1)
        }
    }
}

// ---------------------------------------------------------------------------
extern "C" void kernel_launch(void* const* d_in, const int* in_sizes, int n_in,
                              void* d_out, int out_size, void* d_ws, size_t ws_size,
                              hipStream_t stream)
{
    const float* x     = (const float*)d_in[0];
    const float* Wih0  = (const float*)d_in[1];
    const float* Whh0  = (const float*)d_in[2];
    const float* b0    = (const float*)d_in[3];
    const float* Wih1  = (const float*)d_in[4];
    const float* Whh1  = (const float*)d_in[5];
    const float* b1    = (const float*)d_in[6];
    const float* h0    = (const float*)d_in[7];
    const float* c0    = (const float*)d_in[8];
    const float* headw = (const float*)d_in[9];
    const float* headb = (const float*)d_in[10];
    float* out = (float*)d_out;

    char* ws = (char*)d_ws;
    const size_t h0bytes = (size_t)BATCH * LSEQ * HDIM * sizeof(float);    // 100.7 MB
    const size_t xpbytes = (size_t)BATCH * 2 * TCH * G4 * sizeof(float);   // 25.2 MB
    const size_t h1bytes = (size_t)BATCH * 2 * TCH * HDIM * sizeof(float); // 6.3 MB

    float* h0buf = (float*)ws;
    float* xpbuf = (float*)(ws + h0bytes);
    float* h1buf = (float*)(ws + h0bytes + xpbytes);
    int*   flags = (int*)  (ws + h0bytes + xpbytes + h1bytes);

    init_flags<<<1, 64, 0, stream>>>(flags);
    lstm_pipe<<<32, 768, 0, stream>>>(x, Wih0, Whh0, b0, Wih1, Whh1, b1,
                                      h0, c0, headw, headb,
                                      h0buf, xpbuf, h1buf, flags, out);
}